// Round 9
// baseline (558.080 us; speedup 1.0000x reference)
//
#include <hip/hip_runtime.h>
#include <math.h>

// Problem constants
constexpr int B  = 8;
constexpr int C  = 256;   // Cin
constexpr int M  = 256;
constexpr int O  = 256;
constexpr int H  = 128;
constexpr int W  = 128;
constexpr int HW = H * W; // 16384
constexpr int K  = 128;   // top-k / kept channels

using f16   = _Float16;
using f16x2 = __attribute__((ext_vector_type(2))) _Float16;
using f16x8 = __attribute__((ext_vector_type(8))) _Float16;
using f32x4 = __attribute__((ext_vector_type(4))) float;

// Workspace layout (offsets in float units)
constexpr size_t WS_MEANX = 0;        // 2048
constexpr size_t WS_MASK  = 2048;     // 2048
constexpr size_t WS_G2    = 4096;     // 2048
constexpr size_t WS_OFF   = 6144;     // 48 (pad to 64)
constexpr size_t WS_WE3   = 6208;     // 9216
constexpr size_t WS_WE5   = 15424;    // 25600
constexpr size_t WS_WE7   = 41024;    // 50176
constexpr size_t WS_WT1G  = 91200;    // 65536 f16 (pw1_w fragment-linear)
constexpr size_t WS_WT2G  = 123968;   // 98304 f16 (pw_w[:, :384] fragment-linear)
constexpr size_t WS_SELH  = 173120;   // B*K*HW f16 = 8388608 float slots (33.5 MB)
// BIG region: union of xh (B*C*HW f16, dead after kCm) and yh2 (3*B*K*HW f16)
constexpr size_t WS_BIG   = 8561728;
// end = 33727552 floats = 134.91 MB (same proven footprint as before)

// ---------------------------------------------------------------------------
// Kernel T: fragment-linear f16 weight copies + zero meanx/gap2sum.
// Also warm-read fc1_w/fc2_w into L3 for kB.
// ---------------------------------------------------------------------------
__global__ __launch_bounds__(256) void kT(const float* __restrict__ pw1_w,
                                          const float* __restrict__ pw_w,
                                          const float* __restrict__ fc1_w,
                                          const float* __restrict__ fc2_w,
                                          float* __restrict__ ws) {
  f16* wt1g = (f16*)(ws + WS_WT1G);
  f16* wt2g = (f16*)(ws + WS_WT2G);
  int t = blockIdx.x * 256 + threadIdx.x;
  if (t < 65536) {
    int ks = t >> 13, fr = (t >> 9) & 15, l = (t >> 3) & 63, j = t & 7;
    int o = fr * 16 + (l & 15);
    int c = ks * 32 + ((l >> 4) << 3) + j;
    wt1g[t] = (f16)pw1_w[o * C + c];
  }
  if (t < 98304) {
    int ks = t >> 13, fr = (t >> 9) & 15, l = (t >> 3) & 63, j = t & 7;
    int o = fr * 16 + (l & 15);
    int cc = ks * 32 + ((l >> 4) << 3) + j;
    wt2g[t] = (f16)pw_w[(size_t)o * 768 + cc];
  }
  if (t < 2048) {
    ws[WS_MEANX + t] = 0.f;
    ws[WS_G2 + t]    = 0.f;
  }
  // L3 warm for kB: fc1_w (512x256) + fc2_w (256x512), 32768 float4 each.
  if (t < 32768) {
    float4 a = ((const float4*)fc1_w)[t];
    float4 c = ((const float4*)fc2_w)[t];
    float dead = a.x + a.y + a.z + a.w + c.x + c.y + c.z + c.w;
    asm volatile("" :: "v"(dead));  // keep reads live without storing
  }
}

// ---------------------------------------------------------------------------
// Kernel AT: read x once; per-channel means (atomic partials) and xh = f16 x
// in octet-interleaved layout xh[((b*32+ko)*HW + p)*8 + j], k = 8ko+j.
// ---------------------------------------------------------------------------
__global__ __launch_bounds__(256) void kAT(const float* __restrict__ x,
                                           float* __restrict__ ws) {
  float* meanx = ws + WS_MEANX;
  f16* xh      = (f16*)(ws + WS_BIG);
  int b = blockIdx.z, ko = blockIdx.y, p0 = blockIdx.x * 256;
  __shared__ float sx[8][256];
  int t = threadIdx.x;
  int c8 = t >> 5, pg = t & 31;
  const float* xp = x + (size_t)(b * 256 + ko * 8 + c8) * HW + p0 + pg * 8;
  float4 v0 = ((const float4*)xp)[0];
  float4 v1 = ((const float4*)xp)[1];
  *(float4*)&sx[c8][pg * 8]     = v0;
  *(float4*)&sx[c8][pg * 8 + 4] = v1;
  float s = v0.x + v0.y + v0.z + v0.w + v1.x + v1.y + v1.z + v1.w;
#pragma unroll
  for (int off = 16; off > 0; off >>= 1) s += __shfl_xor(s, off, 32);
  if (pg == 0) atomicAdd(&meanx[b * 256 + ko * 8 + c8], s * (1.f / HW));
  __syncthreads();
  f16x8 o;
#pragma unroll
  for (int j = 0; j < 8; j++) o[j] = (f16)sx[j][t];
  *(f16x8*)&xh[((size_t)(b * 32 + ko) * HW + p0 + t) * 8] = o;
}

// ---------------------------------------------------------------------------
// Kernel B: per-batch block; exact fp32 scoring path (unchanged).
// ---------------------------------------------------------------------------
__global__ __launch_bounds__(256) void kB(const float* __restrict__ pw1_w,
                                          const float* __restrict__ pw1_b,
                                          const float* __restrict__ fc1_w,
                                          const float* __restrict__ fc1_b,
                                          const float* __restrict__ fc2_w,
                                          const float* __restrict__ fc2_b,
                                          float* __restrict__ ws) {
  int b = blockIdx.x;
  const float* meanx = ws + WS_MEANX + b * C;
  float* maskg = ws + WS_MASK;
  __shared__ float s_gap[M];
  __shared__ float s_hid[512];
  __shared__ float s_sc[M];
  int t = threadIdx.x;
  int lane = t & 63, wv = t >> 6;

  float4 mx = ((const float4*)meanx)[lane];
  for (int o0 = wv * 64; o0 < wv * 64 + 64; o0 += 4) {
    float s[4];
#pragma unroll
    for (int j = 0; j < 4; j++) {
      float4 w = ((const float4*)(pw1_w + (size_t)(o0 + j) * C))[lane];
      s[j] = mx.x * w.x + mx.y * w.y + mx.z * w.z + mx.w * w.w;
    }
#pragma unroll
    for (int off = 32; off > 0; off >>= 1)
#pragma unroll
      for (int j = 0; j < 4; j++) s[j] += __shfl_xor(s[j], off, 64);
    if (lane == 0) {
#pragma unroll
      for (int j = 0; j < 4; j++) s_gap[o0 + j] = s[j] + pw1_b[o0 + j];
    }
  }
  __syncthreads();

  float4 g4 = ((const float4*)s_gap)[lane];
  for (int j0 = wv * 128; j0 < wv * 128 + 128; j0 += 4) {
    float s[4];
#pragma unroll
    for (int j = 0; j < 4; j++) {
      float4 w = ((const float4*)(fc1_w + (size_t)(j0 + j) * M))[lane];
      s[j] = g4.x * w.x + g4.y * w.y + g4.z * w.z + g4.w * w.w;
    }
#pragma unroll
    for (int off = 32; off > 0; off >>= 1)
#pragma unroll
      for (int j = 0; j < 4; j++) s[j] += __shfl_xor(s[j], off, 64);
    if (lane == 0) {
#pragma unroll
      for (int j = 0; j < 4; j++) {
        float v = s[j] + fc1_b[j0 + j];
        s_hid[j0 + j] = v > 0.f ? v : 0.f;
      }
    }
  }
  __syncthreads();

  float4 h0 = ((const float4*)s_hid)[lane];
  float4 h1 = ((const float4*)s_hid)[lane + 64];
  for (int o0 = wv * 64; o0 < wv * 64 + 64; o0 += 4) {
    float s[4];
#pragma unroll
    for (int j = 0; j < 4; j++) {
      const float4* wr = (const float4*)(fc2_w + (size_t)(o0 + j) * 512);
      float4 w0 = wr[lane];
      float4 w1 = wr[lane + 64];
      s[j] = h0.x * w0.x + h0.y * w0.y + h0.z * w0.z + h0.w * w0.w +
             h1.x * w1.x + h1.y * w1.y + h1.z * w1.z + h1.w * w1.w;
    }
#pragma unroll
    for (int off = 32; off > 0; off >>= 1)
#pragma unroll
      for (int j = 0; j < 4; j++) s[j] += __shfl_xor(s[j], off, 64);
    if (lane == 0) {
#pragma unroll
      for (int j = 0; j < 4; j++) {
        float v = s[j] + fc2_b[o0 + j];
        s_sc[o0 + j] = 1.f / (1.f + expf(-v));
      }
    }
  }
  __syncthreads();

  {
    int j = t;
    float sj = s_sc[j];
    int cnt = 0;
    for (int m = 0; m < M; m++) {
      float sm = s_sc[m];
      cnt += (sm > sj) || (sm == sj && m < j);
    }
    maskg[b * M + j] = (cnt < K) ? 1.f : 0.f;
  }
}

// ---------------------------------------------------------------------------
// Kernel Cm: h = relu(pw1(x)) via f16 MFMA. B-tile (32 KB, all 8 k-steps)
// staged in LDS ONCE per block (coalesced reg-staging, identity layout,
// single barrier) -> k-loop has zero global B traffic and B is read once
// per block instead of once per wave (4x traffic cut). A double-buffered
// from L2, issued one step ahead. Bias folded into acc init.
// ---------------------------------------------------------------------------
__global__ __launch_bounds__(256) void kCm(const float* __restrict__ pw1_b,
                                           float* __restrict__ ws) {
  const f16* wt1g = (const f16*)(ws + WS_WT1G);
  const f16* xh   = (const f16*)(ws + WS_BIG);
  float* gap2sum  = ws + WS_G2;
  f16* selh       = (f16*)(ws + WS_SELH);
  __shared__ f16 Bs[32 * 512];  // [chunk ko 0..31][px 0..63][8 f16] = 32 KB
  int b  = blockIdx.z;
  int p0 = blockIdx.x * 64;

  int t = threadIdx.x, l = t & 63, w = t >> 6;
  int q = l >> 4, n = l & 15;

  // Stage B-tile: slot s = t + i*256 -> chunk ko = s>>6, lane ll = s&63.
  {
    f16x8 tmp[8];
#pragma unroll
    for (int i = 0; i < 8; i++) {
      int s = t + i * 256;
      int ko = s >> 6, ll = s & 63;
      tmp[i] = *(const f16x8*)&xh[((size_t)(b * 32 + ko) * HW + p0 + ll) * 8];
    }
#pragma unroll
    for (int i = 0; i < 8; i++)
      *(f16x8*)&Bs[(size_t)(t + i * 256) * 8] = tmp[i];
  }

  f32x4 acc[4][4];
#pragma unroll
  for (int mt = 0; mt < 4; mt++) {
    int obase = w * 64 + mt * 16 + q * 4;
#pragma unroll
    for (int nt = 0; nt < 4; nt++)
#pragma unroll
      for (int r = 0; r < 4; r++) acc[mt][nt][r] = pw1_b[obase + r];
  }
  __syncthreads();

  const f16* abase = wt1g + (size_t)(w * 4) * 512 + (size_t)l * 8;

#define LDA1(dst, ks)                                                          \
  _Pragma("unroll") for (int mt = 0; mt < 4; mt++)                             \
      dst[mt] = *(const f16x8*)(abase + (size_t)((ks) * 16 + mt) * 512);
#define LDBS1(dst, ks)                                                         \
  _Pragma("unroll") for (int nt = 0; nt < 4; nt++)                             \
      dst[nt] = *(const f16x8*)&Bs[(size_t)(((ks) * 4 + q) * 64 + nt * 16 + n) * 8];
#define STEP1(af, bf)                                                          \
  _Pragma("unroll") for (int mt = 0; mt < 4; mt++)                             \
      _Pragma("unroll") for (int nt = 0; nt < 4; nt++)                         \
          acc[mt][nt] = __builtin_amdgcn_mfma_f32_16x16x32_f16(                \
              af[mt], bf[nt], acc[mt][nt], 0, 0, 0);

  f16x8 aA[4], aB[4], bC[4], bD[4];
  LDA1(aA, 0)
#pragma unroll
  for (int ks = 0; ks < 8; ks += 2) {
    if (ks + 1 < 8) LDA1(aB, ks + 1)
    LDBS1(bC, ks)
    STEP1(aA, bC)
    if (ks + 2 < 8) LDA1(aA, ks + 2)
    if (ks + 1 < 8) { LDBS1(bD, ks + 1) STEP1(aB, bD) }
  }
#undef LDA1
#undef LDBS1
#undef STEP1

  // Epilogue: relu; sel f16 store (o<128); gap2sum partial sums
#pragma unroll
  for (int mt = 0; mt < 4; mt++) {
    float rsum[4] = {0.f, 0.f, 0.f, 0.f};
    int obase = w * 64 + mt * 16 + q * 4;
#pragma unroll
    for (int nt = 0; nt < 4; nt++) {
      int p = p0 + nt * 16 + n;
#pragma unroll
      for (int r = 0; r < 4; r++) {
        float h = acc[mt][nt][r];
        h = h > 0.f ? h : 0.f;
        rsum[r] += h;
        int o = obase + r;
        if (o < K) selh[((size_t)(b * K + o)) * HW + p] = (f16)h;
      }
    }
#pragma unroll
    for (int off = 1; off < 16; off <<= 1)
#pragma unroll
      for (int r = 0; r < 4; r++) rsum[r] += __shfl_xor(rsum[r], off, 64);
    if (n == 0) {
#pragma unroll
      for (int r = 0; r < 4; r++)
        atomicAdd(&gap2sum[b * M + obase + r], rsum[r]);
    }
  }
}

// ---------------------------------------------------------------------------
// Kernel D1 (1 block): offsets from gap2; emit per-(b,branch) scale/shift.
// ---------------------------------------------------------------------------
__global__ __launch_bounds__(256) void kD1(const float* __restrict__ off_w,
                                           const float* __restrict__ off_b,
                                           float* __restrict__ ws) {
  const float* gap2sum = ws + WS_G2;
  float* offv = ws + WS_OFF;  // [0..23]=scale(b*3+i), [24..47]=shift
  __shared__ float s_off[48];
  int t = threadIdx.x;
  int lane = t & 63, wv = t >> 6;
  for (int id = wv; id < 48; id += 4) {
    int b = id / 6, j = id % 6;
    float4 g = ((const float4*)(gap2sum + b * M))[lane];
    float4 w = ((const float4*)(off_w + (size_t)j * M))[lane];
    float s = (g.x * w.x + g.y * w.y + g.z * w.z + g.w * w.w) * (1.f / HW);
#pragma unroll
    for (int off = 32; off > 0; off >>= 1) s += __shfl_xor(s, off, 64);
    if (lane == 0) s_off[id] = tanhf(s + off_b[j]);
  }
  __syncthreads();
  if (t < 24) {
    int b = t / 3, i = t % 3;
    offv[t]      = 1.f + 1.f / (1.f + expf(-s_off[b * 6 + 2 * i]));
    offv[24 + t] = tanhf(s_off[b * 6 + 2 * i + 1]);
  }
}

// ---------------------------------------------------------------------------
// Kernel D2: effective depthwise weights, with top-k mask folded in.
// ---------------------------------------------------------------------------
__global__ __launch_bounds__(256) void kD2(const float* __restrict__ dw3,
                                           const float* __restrict__ dw5,
                                           const float* __restrict__ dw7,
                                           float* __restrict__ ws) {
  const float* offv  = ws + WS_OFF;
  const float* maskg = ws + WS_MASK;
  float* wE3 = ws + WS_WE3;
  float* wE5 = ws + WS_WE5;
  float* wE7 = ws + WS_WE7;
  int tid = blockIdx.x * 256 + threadIdx.x;
  int stride = gridDim.x * 256;
  for (int i = tid; i < B * K * 9; i += stride) {
    int b = i / (K * 9), rem = i % (K * 9), c = rem / 9;
    wE3[i] = (dw3[rem] * offv[b * 3 + 0] + offv[24 + b * 3 + 0]) * maskg[b * M + c];
  }
  for (int i = tid; i < B * K * 25; i += stride) {
    int b = i / (K * 25), rem = i % (K * 25), c = rem / 25;
    wE5[i] = (dw5[rem] * offv[b * 3 + 1] + offv[24 + b * 3 + 1]) * maskg[b * M + c];
  }
  for (int i = tid; i < B * K * 49; i += stride) {
    int b = i / (K * 49), rem = i % (K * 49), c = rem / 49;
    wE7[i] = (dw7[rem] * offv[b * 3 + 2] + offv[24 + b * 3 + 2]) * maskg[b * M + c];
  }
}

// ---------------------------------------------------------------------------
// Kernel Em: merged depthwise conv. f16 halo in LDS; compute = f16x2 LDS
// reads -> cvt -> fp32 fma. Vectorized fill: halo row origin c0-8 is
// 8-aligned -> pure f16x8 chunks. Plane stride 1768 f16 (884 dw % 32 = 20).
// Block: 256 thr = 8 ch x 32 col-pairs; 16 rows x 64 cols x 8 ch per block.
// ---------------------------------------------------------------------------
__global__ __launch_bounds__(256) void kEm(const float* __restrict__ ws_ro,
                                           float* __restrict__ ws) {
  constexpr int SP = 1768;  // f16 per channel plane (22 rows x 80 + pad)
  __shared__ f16 sm[8 * SP];  // 28288 B
  const f16* selh = (const f16*)(ws_ro + WS_SELH);
  f16* yh2        = (f16*)(ws + WS_BIG);
  int bx = blockIdx.x;
  int slab = bx >> 1, chalf = bx & 1;
  int ko = blockIdx.y, b = blockIdx.z;
  int r0 = slab * 16, c0 = chalf * 64;

  // Fill: per (ch, row rr of 22, chunk of 10): one f16x8 from global or zeros.
  // LDS row col L corresponds to global col c0 - 8 + L.
  for (int i = threadIdx.x; i < 8 * 220; i += 256) {
    int chn = i / 220, rem = i - chn * 220;
    int rr = rem / 10, chunk = rem - rr * 10;
    int gy = r0 - 3 + rr, g0 = c0 - 8 + chunk * 8;
    f16x8 v = {};
    if (gy >= 0 && gy < H && g0 >= 0 && g0 < W)
      v = *(const f16x8*)&selh[(size_t)(b * 128 + ko * 8 + chn) * HW + gy * W + g0];
    *(f16x8*)&sm[chn * SP + rr * 80 + chunk * 8] = v;
  }
  __syncthreads();

  int t = threadIdx.x;
  int ch = t & 7, cp = t >> 3;  // channel 0..7, col-pair 0..31
  int cglob = c0 + cp * 2;

  // Tap f16-index within the vv window: even col: (8-P)+dx-2*SOFF,
  // odd col: (9-P)+dx-2*SOFF. (KS,NW,SOFF) = (3,3,3),(5,3,3),(7,5,2).
#define CONV_BRANCH(KS, BR, WSOFF, NW, SOFF)                                   \
  {                                                                            \
    constexpr int P = (KS - 1) / 2;                                            \
    const float* wp = ws_ro + WSOFF + (size_t)(b * 128 + ko * 8 + ch) * (KS*KS); \
    float w[KS * KS];                                                          \
    _Pragma("unroll") for (int i = 0; i < KS * KS; i++) w[i] = wp[i];          \
    float a0[16], a1[16];                                                      \
    _Pragma("unroll") for (int r = 0; r < 16; r++) { a0[r] = 0.f; a1[r] = 0.f; } \
    _Pragma("unroll") for (int iy = 0; iy < 16 + 2 * P; iy++) {                \
      int hr = iy + (3 - P);                                                   \
      const f16x2* rowp = (const f16x2*)(sm + ch * SP + hr * 80);              \
      float vv[2 * NW];                                                        \
      _Pragma("unroll") for (int u = 0; u < NW; u++) {                         \
        f16x2 pr = rowp[cp + SOFF + u];                                        \
        vv[2 * u]     = (float)pr[0];                                          \
        vv[2 * u + 1] = (float)pr[1];                                          \
      }                                                                        \
      _Pragma("unroll") for (int rr = 0; rr < 16; rr++) {                      \
        int dy = iy - rr;                                                      \
        if (dy >= 0 && dy < KS) {                                              \
          _Pragma("unroll") for (int dx = 0; dx < KS; dx++) {                  \
            int m = (8 - P) + dx - 2 * SOFF;                                   \
            a0[rr] += vv[m]     * w[dy * KS + dx];                             \
            a1[rr] += vv[m + 1] * w[dy * KS + dx];                             \
          }                                                                    \
        }                                                                      \
      }                                                                        \
    }                                                                          \
    f16* op = yh2 + (size_t)(b * 48 + BR * 16 + ko) * HW * 8;                  \
    _Pragma("unroll") for (int rr = 0; rr < 16; rr++) {                        \
      size_t pa = ((size_t)(r0 + rr) * W + cglob) * 8 + ch;                    \
      op[pa]     = (f16)a0[rr];                                                \
      op[pa + 8] = (f16)a1[rr];                                                \
    }                                                                          \
  }

  CONV_BRANCH(3, 0, WS_WE3, 3, 3)
  CONV_BRANCH(5, 1, WS_WE5, 3, 3)
  CONV_BRANCH(7, 2, WS_WE7, 5, 2)
#undef CONV_BRANCH
}

// ---------------------------------------------------------------------------
// Kernel Fm: merged final pointwise, f16 MFMA, K=384. B-tile (48 KB, all 12
// k-steps) staged in LDS once per block; single barrier; k-loop = ds_read +
// L2 A double-buffer + MFMA, zero global B latency. Residual + bias folded
// into acc init (x loads issued pre-barrier, complete under it; nontemporal).
// ---------------------------------------------------------------------------
__global__ __launch_bounds__(256) void kFm(const float* __restrict__ x,
                                           const float* __restrict__ pw_b,
                                           const float* __restrict__ ws,
                                           float* __restrict__ out) {
  const f16* wt2g = (const f16*)(ws + WS_WT2G);
  const f16* yh2  = (const f16*)(ws + WS_BIG);
  __shared__ f16 Bs[48 * 512];  // [chunk 0..47][px 0..63][8 f16] = 48 KB
  int b  = blockIdx.z;
  int p0 = blockIdx.x * 64;

  int t = threadIdx.x, l = t & 63, w = t >> 6;
  int q = l >> 4, n = l & 15;

  // Stage B-tile: 12 slots of 16B per thread.
  {
    f16x8 tmp[12];
#pragma unroll
    for (int i = 0; i < 12; i++) {
      int s = t + i * 256;
      int ko = s >> 6, ll = s & 63;
      tmp[i] = *(const f16x8*)&yh2[((size_t)(b * 48 + ko) * HW + p0 + ll) * 8];
    }
#pragma unroll
    for (int i = 0; i < 12; i++)
      *(f16x8*)&Bs[(size_t)(t + i * 256) * 8] = tmp[i];
  }

  f32x4 acc[4][4];
#pragma unroll
  for (int mt = 0; mt < 4; mt++) {
    int obase = w * 64 + mt * 16 + q * 4;
    float b4[4];
#pragma unroll
    for (int r = 0; r < 4; r++) b4[r] = pw_b[obase + r];
#pragma unroll
    for (int nt = 0; nt < 4; nt++) {
      int p = p0 + nt * 16 + n;
#pragma unroll
      for (int r = 0; r < 4; r++) {
        size_t idx = ((size_t)b * O + obase + r) * HW + p;
        acc[mt][nt][r] = b4[r] + __builtin_nontemporal_load(&x[idx]);
      }
    }
  }
  __syncthreads();

  const f16* abase = wt2g + (size_t)(w * 4) * 512 + (size_t)l * 8;

#define LDA2(dst, ks)                                                          \
  _Pragma("unroll") for (int mt = 0; mt < 4; mt++)                             \
      dst[mt] = *(const f16x8*)(abase + (size_t)((ks) * 16 + mt) * 512);
#define LDBS2(dst, ks)                                                         \
  _Pragma("unroll") for (int nt = 0; nt < 4; nt++)                             \
      dst[nt] = *(const f16x8*)&Bs[(size_t)(((ks) * 4 + q) * 64 + nt * 16 + n) * 8];
#define STEP2(af, bf)                                                          \
  _Pragma("unroll") for (int mt = 0; mt < 4; mt++)                             \
      _Pragma("unroll") for (int nt = 0; nt < 4; nt++)                         \
          acc[mt][nt] = __builtin_amdgcn_mfma_f32_16x16x32_f16(                \
              af[mt], bf[nt], acc[mt][nt], 0, 0, 0);

  f16x8 aA[4], aB[4], bC[4], bD[4];
  LDA2(aA, 0)
#pragma unroll
  for (int ks = 0; ks < 12; ks += 2) {
    if (ks + 1 < 12) LDA2(aB, ks + 1)
    LDBS2(bC, ks)
    STEP2(aA, bC)
    if (ks + 2 < 12) LDA2(aA, ks + 2)
    if (ks + 1 < 12) { LDBS2(bD, ks + 1) STEP2(aB, bD) }
  }
#undef LDA2
#undef LDBS2
#undef STEP2

#pragma unroll
  for (int mt = 0; mt < 4; mt++) {
    int obase = w * 64 + mt * 16 + q * 4;
#pragma unroll
    for (int nt = 0; nt < 4; nt++) {
      int p = p0 + nt * 16 + n;
#pragma unroll
      for (int r = 0; r < 4; r++) {
        size_t idx = ((size_t)b * O + obase + r) * HW + p;
        out[idx] = acc[mt][nt][r];
      }
    }
  }
}

// ---------------------------------------------------------------------------
extern "C" void kernel_launch(void* const* d_in, const int* in_sizes, int n_in,
                              void* d_out, int out_size, void* d_ws, size_t ws_size,
                              hipStream_t stream) {
  const float* x     = (const float*)d_in[0];
  const float* pw1_w = (const float*)d_in[1];
  const float* pw1_b = (const float*)d_in[2];
  const float* fc1_w = (const float*)d_in[3];
  const float* fc1_b = (const float*)d_in[4];
  const float* fc2_w = (const float*)d_in[5];
  const float* fc2_b = (const float*)d_in[6];
  const float* off_w = (const float*)d_in[7];
  const float* off_b = (const float*)d_in[8];
  const float* dw3   = (const float*)d_in[9];
  const float* dw5   = (const float*)d_in[10];
  const float* dw7   = (const float*)d_in[11];
  const float* pw_w  = (const float*)d_in[12];
  const float* pw_b  = (const float*)d_in[13];
  float* out = (float*)d_out;
  float* ws  = (float*)d_ws;

  kT<<<384, 256, 0, stream>>>(pw1_w, pw_w, fc1_w, fc2_w, ws);
  kAT<<<dim3(HW / 256, 32, B), 256, 0, stream>>>(x, ws);
  kB<<<B, 256, 0, stream>>>(pw1_w, pw1_b, fc1_w, fc1_b, fc2_w, fc2_b, ws);
  kCm<<<dim3(HW / 64, 1, B), 256, 0, stream>>>(pw1_b, ws);
  kD1<<<1, 256, 0, stream>>>(off_w, off_b, ws);
  kD2<<<84, 256, 0, stream>>>(dw3, dw5, dw7, ws);
  kEm<<<dim3(16, 16, B), 256, 0, stream>>>(ws, ws);
  kFm<<<dim3(HW / 64, 1, B), 256, 0, stream>>>(x, pw_b, ws, out);
}

// Round 10
// 547.135 us; speedup vs baseline: 1.0200x; 1.0200x over previous
//
#include <hip/hip_runtime.h>
#include <math.h>

// Problem constants
constexpr int B  = 8;
constexpr int C  = 256;   // Cin
constexpr int M  = 256;
constexpr int O  = 256;
constexpr int H  = 128;
constexpr int W  = 128;
constexpr int HW = H * W; // 16384
constexpr int K  = 128;   // top-k / kept channels

using f16   = _Float16;
using f16x2 = __attribute__((ext_vector_type(2))) _Float16;
using f16x8 = __attribute__((ext_vector_type(8))) _Float16;
using f32x4 = __attribute__((ext_vector_type(4))) float;

// Workspace layout (offsets in float units)
constexpr size_t WS_MEANX = 0;        // 2048
constexpr size_t WS_MASK  = 2048;     // 2048
constexpr size_t WS_G2    = 4096;     // 2048
constexpr size_t WS_OFF   = 6144;     // 48 (pad to 64)
constexpr size_t WS_WE3   = 6208;     // 9216
constexpr size_t WS_WE5   = 15424;    // 25600
constexpr size_t WS_WE7   = 41024;    // 50176
constexpr size_t WS_WT1G  = 91200;    // 65536 f16 (pw1_w fragment-linear)
constexpr size_t WS_WT2G  = 123968;   // 98304 f16 (pw_w[:, :384] fragment-linear)
constexpr size_t WS_SELH  = 173120;   // B*K*HW f16 = 8388608 float slots (33.5 MB)
// BIG region: union of xh (B*C*HW f16, dead after kCm) and yh2 (3*B*K*HW f16)
constexpr size_t WS_BIG   = 8561728;
// end = 33727552 floats = 134.91 MB (same proven footprint as before)

// ---------------------------------------------------------------------------
// Kernel T: fragment-linear f16 weight copies + zero meanx/gap2sum.
// Also warm-read fc1_w/fc2_w into L3 for kB.
// ---------------------------------------------------------------------------
__global__ __launch_bounds__(256) void kT(const float* __restrict__ pw1_w,
                                          const float* __restrict__ pw_w,
                                          const float* __restrict__ fc1_w,
                                          const float* __restrict__ fc2_w,
                                          float* __restrict__ ws) {
  f16* wt1g = (f16*)(ws + WS_WT1G);
  f16* wt2g = (f16*)(ws + WS_WT2G);
  int t = blockIdx.x * 256 + threadIdx.x;
  if (t < 65536) {
    int ks = t >> 13, fr = (t >> 9) & 15, l = (t >> 3) & 63, j = t & 7;
    int o = fr * 16 + (l & 15);
    int c = ks * 32 + ((l >> 4) << 3) + j;
    wt1g[t] = (f16)pw1_w[o * C + c];
  }
  if (t < 98304) {
    int ks = t >> 13, fr = (t >> 9) & 15, l = (t >> 3) & 63, j = t & 7;
    int o = fr * 16 + (l & 15);
    int cc = ks * 32 + ((l >> 4) << 3) + j;
    wt2g[t] = (f16)pw_w[(size_t)o * 768 + cc];
  }
  if (t < 2048) {
    ws[WS_MEANX + t] = 0.f;
    ws[WS_G2 + t]    = 0.f;
  }
  // L3 warm for kB: fc1_w (512x256) + fc2_w (256x512), 32768 float4 each.
  if (t < 32768) {
    float4 a = ((const float4*)fc1_w)[t];
    float4 c = ((const float4*)fc2_w)[t];
    float dead = a.x + a.y + a.z + a.w + c.x + c.y + c.z + c.w;
    asm volatile("" :: "v"(dead));  // keep reads live without storing
  }
}

// ---------------------------------------------------------------------------
// Kernel AT: read x once; per-channel means (atomic partials) and xh = f16 x
// in octet-interleaved layout xh[((b*32+ko)*HW + p)*8 + j], k = 8ko+j.
// ---------------------------------------------------------------------------
__global__ __launch_bounds__(256) void kAT(const float* __restrict__ x,
                                           float* __restrict__ ws) {
  float* meanx = ws + WS_MEANX;
  f16* xh      = (f16*)(ws + WS_BIG);
  int b = blockIdx.z, ko = blockIdx.y, p0 = blockIdx.x * 256;
  __shared__ float sx[8][256];
  int t = threadIdx.x;
  int c8 = t >> 5, pg = t & 31;
  const float* xp = x + (size_t)(b * 256 + ko * 8 + c8) * HW + p0 + pg * 8;
  float4 v0 = ((const float4*)xp)[0];
  float4 v1 = ((const float4*)xp)[1];
  *(float4*)&sx[c8][pg * 8]     = v0;
  *(float4*)&sx[c8][pg * 8 + 4] = v1;
  float s = v0.x + v0.y + v0.z + v0.w + v1.x + v1.y + v1.z + v1.w;
#pragma unroll
  for (int off = 16; off > 0; off >>= 1) s += __shfl_xor(s, off, 32);
  if (pg == 0) atomicAdd(&meanx[b * 256 + ko * 8 + c8], s * (1.f / HW));
  __syncthreads();
  f16x8 o;
#pragma unroll
  for (int j = 0; j < 8; j++) o[j] = (f16)sx[j][t];
  *(f16x8*)&xh[((size_t)(b * 32 + ko) * HW + p0 + t) * 8] = o;
}

// ---------------------------------------------------------------------------
// Kernel B: per-batch block; exact fp32 scoring path (unchanged).
// ---------------------------------------------------------------------------
__global__ __launch_bounds__(256) void kB(const float* __restrict__ pw1_w,
                                          const float* __restrict__ pw1_b,
                                          const float* __restrict__ fc1_w,
                                          const float* __restrict__ fc1_b,
                                          const float* __restrict__ fc2_w,
                                          const float* __restrict__ fc2_b,
                                          float* __restrict__ ws) {
  int b = blockIdx.x;
  const float* meanx = ws + WS_MEANX + b * C;
  float* maskg = ws + WS_MASK;
  __shared__ float s_gap[M];
  __shared__ float s_hid[512];
  __shared__ float s_sc[M];
  int t = threadIdx.x;
  int lane = t & 63, wv = t >> 6;

  float4 mx = ((const float4*)meanx)[lane];
  for (int o0 = wv * 64; o0 < wv * 64 + 64; o0 += 4) {
    float s[4];
#pragma unroll
    for (int j = 0; j < 4; j++) {
      float4 w = ((const float4*)(pw1_w + (size_t)(o0 + j) * C))[lane];
      s[j] = mx.x * w.x + mx.y * w.y + mx.z * w.z + mx.w * w.w;
    }
#pragma unroll
    for (int off = 32; off > 0; off >>= 1)
#pragma unroll
      for (int j = 0; j < 4; j++) s[j] += __shfl_xor(s[j], off, 64);
    if (lane == 0) {
#pragma unroll
      for (int j = 0; j < 4; j++) s_gap[o0 + j] = s[j] + pw1_b[o0 + j];
    }
  }
  __syncthreads();

  float4 g4 = ((const float4*)s_gap)[lane];
  for (int j0 = wv * 128; j0 < wv * 128 + 128; j0 += 4) {
    float s[4];
#pragma unroll
    for (int j = 0; j < 4; j++) {
      float4 w = ((const float4*)(fc1_w + (size_t)(j0 + j) * M))[lane];
      s[j] = g4.x * w.x + g4.y * w.y + g4.z * w.z + g4.w * w.w;
    }
#pragma unroll
    for (int off = 32; off > 0; off >>= 1)
#pragma unroll
      for (int j = 0; j < 4; j++) s[j] += __shfl_xor(s[j], off, 64);
    if (lane == 0) {
#pragma unroll
      for (int j = 0; j < 4; j++) {
        float v = s[j] + fc1_b[j0 + j];
        s_hid[j0 + j] = v > 0.f ? v : 0.f;
      }
    }
  }
  __syncthreads();

  float4 h0 = ((const float4*)s_hid)[lane];
  float4 h1 = ((const float4*)s_hid)[lane + 64];
  for (int o0 = wv * 64; o0 < wv * 64 + 64; o0 += 4) {
    float s[4];
#pragma unroll
    for (int j = 0; j < 4; j++) {
      const float4* wr = (const float4*)(fc2_w + (size_t)(o0 + j) * 512);
      float4 w0 = wr[lane];
      float4 w1 = wr[lane + 64];
      s[j] = h0.x * w0.x + h0.y * w0.y + h0.z * w0.z + h0.w * w0.w +
             h1.x * w1.x + h1.y * w1.y + h1.z * w1.z + h1.w * w1.w;
    }
#pragma unroll
    for (int off = 32; off > 0; off >>= 1)
#pragma unroll
      for (int j = 0; j < 4; j++) s[j] += __shfl_xor(s[j], off, 64);
    if (lane == 0) {
#pragma unroll
      for (int j = 0; j < 4; j++) {
        float v = s[j] + fc2_b[o0 + j];
        s_sc[o0 + j] = 1.f / (1.f + expf(-v));
      }
    }
  }
  __syncthreads();

  {
    int j = t;
    float sj = s_sc[j];
    int cnt = 0;
    for (int m = 0; m < M; m++) {
      float sm = s_sc[m];
      cnt += (sm > sj) || (sm == sj && m < j);
    }
    maskg[b * M + j] = (cnt < K) ? 1.f : 0.f;
  }
}

// ---------------------------------------------------------------------------
// Kernel Cm: h = relu(pw1(x)) via f16 MFMA. B-tile (32 KB, all 8 k-steps)
// staged in LDS once per block; single barrier; k-loop = ds_read + L2 A
// double-buffer + MFMA. Bias folded into acc init.
// ---------------------------------------------------------------------------
__global__ __launch_bounds__(256) void kCm(const float* __restrict__ pw1_b,
                                           float* __restrict__ ws) {
  const f16* wt1g = (const f16*)(ws + WS_WT1G);
  const f16* xh   = (const f16*)(ws + WS_BIG);
  float* gap2sum  = ws + WS_G2;
  f16* selh       = (f16*)(ws + WS_SELH);
  __shared__ f16 Bs[32 * 512];  // [chunk ko 0..31][px 0..63][8 f16] = 32 KB
  int b  = blockIdx.z;
  int p0 = blockIdx.x * 64;

  int t = threadIdx.x, l = t & 63, w = t >> 6;
  int q = l >> 4, n = l & 15;

  // Stage B-tile: slot s = t + i*256 -> chunk ko = s>>6, lane ll = s&63.
  {
    f16x8 tmp[8];
#pragma unroll
    for (int i = 0; i < 8; i++) {
      int s = t + i * 256;
      int ko = s >> 6, ll = s & 63;
      tmp[i] = *(const f16x8*)&xh[((size_t)(b * 32 + ko) * HW + p0 + ll) * 8];
    }
#pragma unroll
    for (int i = 0; i < 8; i++)
      *(f16x8*)&Bs[(size_t)(t + i * 256) * 8] = tmp[i];
  }

  f32x4 acc[4][4];
#pragma unroll
  for (int mt = 0; mt < 4; mt++) {
    int obase = w * 64 + mt * 16 + q * 4;
#pragma unroll
    for (int nt = 0; nt < 4; nt++)
#pragma unroll
      for (int r = 0; r < 4; r++) acc[mt][nt][r] = pw1_b[obase + r];
  }
  __syncthreads();

  const f16* abase = wt1g + (size_t)(w * 4) * 512 + (size_t)l * 8;

#define LDA1(dst, ks)                                                          \
  _Pragma("unroll") for (int mt = 0; mt < 4; mt++)                             \
      dst[mt] = *(const f16x8*)(abase + (size_t)((ks) * 16 + mt) * 512);
#define LDBS1(dst, ks)                                                         \
  _Pragma("unroll") for (int nt = 0; nt < 4; nt++)                             \
      dst[nt] = *(const f16x8*)&Bs[(size_t)(((ks) * 4 + q) * 64 + nt * 16 + n) * 8];
#define STEP1(af, bf)                                                          \
  _Pragma("unroll") for (int mt = 0; mt < 4; mt++)                             \
      _Pragma("unroll") for (int nt = 0; nt < 4; nt++)                         \
          acc[mt][nt] = __builtin_amdgcn_mfma_f32_16x16x32_f16(                \
              af[mt], bf[nt], acc[mt][nt], 0, 0, 0);

  f16x8 aA[4], aB[4], bC[4], bD[4];
  LDA1(aA, 0)
#pragma unroll
  for (int ks = 0; ks < 8; ks += 2) {
    if (ks + 1 < 8) LDA1(aB, ks + 1)
    LDBS1(bC, ks)
    STEP1(aA, bC)
    if (ks + 2 < 8) LDA1(aA, ks + 2)
    if (ks + 1 < 8) { LDBS1(bD, ks + 1) STEP1(aB, bD) }
  }
#undef LDA1
#undef LDBS1
#undef STEP1

  // Epilogue: relu; sel f16 store (o<128); gap2sum partial sums
#pragma unroll
  for (int mt = 0; mt < 4; mt++) {
    float rsum[4] = {0.f, 0.f, 0.f, 0.f};
    int obase = w * 64 + mt * 16 + q * 4;
#pragma unroll
    for (int nt = 0; nt < 4; nt++) {
      int p = p0 + nt * 16 + n;
#pragma unroll
      for (int r = 0; r < 4; r++) {
        float h = acc[mt][nt][r];
        h = h > 0.f ? h : 0.f;
        rsum[r] += h;
        int o = obase + r;
        if (o < K) selh[((size_t)(b * K + o)) * HW + p] = (f16)h;
      }
    }
#pragma unroll
    for (int off = 1; off < 16; off <<= 1)
#pragma unroll
      for (int r = 0; r < 4; r++) rsum[r] += __shfl_xor(rsum[r], off, 64);
    if (n == 0) {
#pragma unroll
      for (int r = 0; r < 4; r++)
        atomicAdd(&gap2sum[b * M + obase + r], rsum[r]);
    }
  }
}

// ---------------------------------------------------------------------------
// Kernel D1 (1 block): offsets from gap2; emit per-(b,branch) scale/shift.
// ---------------------------------------------------------------------------
__global__ __launch_bounds__(256) void kD1(const float* __restrict__ off_w,
                                           const float* __restrict__ off_b,
                                           float* __restrict__ ws) {
  const float* gap2sum = ws + WS_G2;
  float* offv = ws + WS_OFF;  // [0..23]=scale(b*3+i), [24..47]=shift
  __shared__ float s_off[48];
  int t = threadIdx.x;
  int lane = t & 63, wv = t >> 6;
  for (int id = wv; id < 48; id += 4) {
    int b = id / 6, j = id % 6;
    float4 g = ((const float4*)(gap2sum + b * M))[lane];
    float4 w = ((const float4*)(off_w + (size_t)j * M))[lane];
    float s = (g.x * w.x + g.y * w.y + g.z * w.z + g.w * w.w) * (1.f / HW);
#pragma unroll
    for (int off = 32; off > 0; off >>= 1) s += __shfl_xor(s, off, 64);
    if (lane == 0) s_off[id] = tanhf(s + off_b[j]);
  }
  __syncthreads();
  if (t < 24) {
    int b = t / 3, i = t % 3;
    offv[t]      = 1.f + 1.f / (1.f + expf(-s_off[b * 6 + 2 * i]));
    offv[24 + t] = tanhf(s_off[b * 6 + 2 * i + 1]);
  }
}

// ---------------------------------------------------------------------------
// Kernel D2: effective depthwise weights, with top-k mask folded in.
// ---------------------------------------------------------------------------
__global__ __launch_bounds__(256) void kD2(const float* __restrict__ dw3,
                                           const float* __restrict__ dw5,
                                           const float* __restrict__ dw7,
                                           float* __restrict__ ws) {
  const float* offv  = ws + WS_OFF;
  const float* maskg = ws + WS_MASK;
  float* wE3 = ws + WS_WE3;
  float* wE5 = ws + WS_WE5;
  float* wE7 = ws + WS_WE7;
  int tid = blockIdx.x * 256 + threadIdx.x;
  int stride = gridDim.x * 256;
  for (int i = tid; i < B * K * 9; i += stride) {
    int b = i / (K * 9), rem = i % (K * 9), c = rem / 9;
    wE3[i] = (dw3[rem] * offv[b * 3 + 0] + offv[24 + b * 3 + 0]) * maskg[b * M + c];
  }
  for (int i = tid; i < B * K * 25; i += stride) {
    int b = i / (K * 25), rem = i % (K * 25), c = rem / 25;
    wE5[i] = (dw5[rem] * offv[b * 3 + 1] + offv[24 + b * 3 + 1]) * maskg[b * M + c];
  }
  for (int i = tid; i < B * K * 49; i += stride) {
    int b = i / (K * 49), rem = i % (K * 49), c = rem / 49;
    wE7[i] = (dw7[rem] * offv[b * 3 + 2] + offv[24 + b * 3 + 2]) * maskg[b * M + c];
  }
}

// ---------------------------------------------------------------------------
// Kernel Em: merged depthwise conv. 8-ROW slabs (was 16): halves per-thread
// serial work (acc 16 floats, ~1700 VALU ops), drops LDS to 18 KB -> more
// blocks/CU + 16 fine scheduling rounds instead of 8 coarse ones. Codegen-
// robustness response to the R9 ±35us swing on unchanged 16-row source.
// Plane stride SP=1128 f16 (564 dw % 32 = 20 -> 8 ch on distinct bank sets).
// Block: 256 thr = 8 ch x 32 col-pairs; 8 rows x 64 cols x 8 ch per block.
// ---------------------------------------------------------------------------
__global__ __launch_bounds__(256) void kEm(const float* __restrict__ ws_ro,
                                           float* __restrict__ ws) {
  constexpr int SP = 1128;  // f16 per channel plane (14 rows x 80 + pad)
  __shared__ f16 sm[8 * SP];  // 18048 B
  const f16* selh = (const f16*)(ws_ro + WS_SELH);
  f16* yh2        = (f16*)(ws + WS_BIG);
  int bx = blockIdx.x;
  int slab = bx >> 1, chalf = bx & 1;
  int ko = blockIdx.y, b = blockIdx.z;
  int r0 = slab * 8, c0 = chalf * 64;

  // Fill: per (ch, row rr of 14, chunk of 10): one f16x8 from global or zeros.
  // LDS row col L corresponds to global col c0 - 8 + L.
  for (int i = threadIdx.x; i < 8 * 140; i += 256) {
    int chn = i / 140, rem = i - chn * 140;
    int rr = rem / 10, chunk = rem - rr * 10;
    int gy = r0 - 3 + rr, g0 = c0 - 8 + chunk * 8;
    f16x8 v = {};
    if (gy >= 0 && gy < H && g0 >= 0 && g0 < W)
      v = *(const f16x8*)&selh[(size_t)(b * 128 + ko * 8 + chn) * HW + gy * W + g0];
    *(f16x8*)&sm[chn * SP + rr * 80 + chunk * 8] = v;
  }
  __syncthreads();

  int t = threadIdx.x;
  int ch = t & 7, cp = t >> 3;  // channel 0..7, col-pair 0..31
  int cglob = c0 + cp * 2;

  // Tap f16-index within the vv window: even col: (8-P)+dx-2*SOFF,
  // odd col: (9-P)+dx-2*SOFF. (KS,NW,SOFF) = (3,3,3),(5,3,3),(7,5,2).
#define CONV_BRANCH(KS, BR, WSOFF, NW, SOFF)                                   \
  {                                                                            \
    constexpr int P = (KS - 1) / 2;                                            \
    const float* wp = ws_ro + WSOFF + (size_t)(b * 128 + ko * 8 + ch) * (KS*KS); \
    float w[KS * KS];                                                          \
    _Pragma("unroll") for (int i = 0; i < KS * KS; i++) w[i] = wp[i];          \
    float a0[8], a1[8];                                                        \
    _Pragma("unroll") for (int r = 0; r < 8; r++) { a0[r] = 0.f; a1[r] = 0.f; } \
    _Pragma("unroll") for (int iy = 0; iy < 8 + 2 * P; iy++) {                 \
      int hr = iy + (3 - P);                                                   \
      const f16x2* rowp = (const f16x2*)(sm + ch * SP + hr * 80);              \
      float vv[2 * NW];                                                        \
      _Pragma("unroll") for (int u = 0; u < NW; u++) {                         \
        f16x2 pr = rowp[cp + SOFF + u];                                        \
        vv[2 * u]     = (float)pr[0];                                          \
        vv[2 * u + 1] = (float)pr[1];                                          \
      }                                                                        \
      _Pragma("unroll") for (int rr = 0; rr < 8; rr++) {                       \
        int dy = iy - rr;                                                      \
        if (dy >= 0 && dy < KS) {                                              \
          _Pragma("unroll") for (int dx = 0; dx < KS; dx++) {                  \
            int m = (8 - P) + dx - 2 * SOFF;                                   \
            a0[rr] += vv[m]     * w[dy * KS + dx];                             \
            a1[rr] += vv[m + 1] * w[dy * KS + dx];                             \
          }                                                                    \
        }                                                                      \
      }                                                                        \
    }                                                                          \
    f16* op = yh2 + (size_t)(b * 48 + BR * 16 + ko) * HW * 8;                  \
    _Pragma("unroll") for (int rr = 0; rr < 8; rr++) {                         \
      size_t pa = ((size_t)(r0 + rr) * W + cglob) * 8 + ch;                    \
      op[pa]     = (f16)a0[rr];                                                \
      op[pa + 8] = (f16)a1[rr];                                                \
    }                                                                          \
  }

  CONV_BRANCH(3, 0, WS_WE3, 3, 3)
  CONV_BRANCH(5, 1, WS_WE5, 3, 3)
  CONV_BRANCH(7, 2, WS_WE7, 5, 2)
#undef CONV_BRANCH
}

// ---------------------------------------------------------------------------
// Kernel Fm: merged final pointwise, f16 MFMA, K=384. B-tile (48 KB, all 12
// k-steps) staged in LDS once per block; single barrier; k-loop = ds_read +
// L2 A double-buffer + MFMA, zero global B latency. Residual + bias folded
// into acc init (x loads issued pre-barrier, complete under it; nontemporal).
// ---------------------------------------------------------------------------
__global__ __launch_bounds__(256) void kFm(const float* __restrict__ x,
                                           const float* __restrict__ pw_b,
                                           const float* __restrict__ ws,
                                           float* __restrict__ out) {
  const f16* wt2g = (const f16*)(ws + WS_WT2G);
  const f16* yh2  = (const f16*)(ws + WS_BIG);
  __shared__ f16 Bs[48 * 512];  // [chunk 0..47][px 0..63][8 f16] = 48 KB
  int b  = blockIdx.z;
  int p0 = blockIdx.x * 64;

  int t = threadIdx.x, l = t & 63, w = t >> 6;
  int q = l >> 4, n = l & 15;

  // Stage B-tile: 12 slots of 16B per thread.
  {
    f16x8 tmp[12];
#pragma unroll
    for (int i = 0; i < 12; i++) {
      int s = t + i * 256;
      int ko = s >> 6, ll = s & 63;
      tmp[i] = *(const f16x8*)&yh2[((size_t)(b * 48 + ko) * HW + p0 + ll) * 8];
    }
#pragma unroll
    for (int i = 0; i < 12; i++)
      *(f16x8*)&Bs[(size_t)(t + i * 256) * 8] = tmp[i];
  }

  f32x4 acc[4][4];
#pragma unroll
  for (int mt = 0; mt < 4; mt++) {
    int obase = w * 64 + mt * 16 + q * 4;
    float b4[4];
#pragma unroll
    for (int r = 0; r < 4; r++) b4[r] = pw_b[obase + r];
#pragma unroll
    for (int nt = 0; nt < 4; nt++) {
      int p = p0 + nt * 16 + n;
#pragma unroll
      for (int r = 0; r < 4; r++) {
        size_t idx = ((size_t)b * O + obase + r) * HW + p;
        acc[mt][nt][r] = b4[r] + __builtin_nontemporal_load(&x[idx]);
      }
    }
  }
  __syncthreads();

  const f16* abase = wt2g + (size_t)(w * 4) * 512 + (size_t)l * 8;

#define LDA2(dst, ks)                                                          \
  _Pragma("unroll") for (int mt = 0; mt < 4; mt++)                             \
      dst[mt] = *(const f16x8*)(abase + (size_t)((ks) * 16 + mt) * 512);
#define LDBS2(dst, ks)                                                         \
  _Pragma("unroll") for (int nt = 0; nt < 4; nt++)                             \
      dst[nt] = *(const f16x8*)&Bs[(size_t)(((ks) * 4 + q) * 64 + nt * 16 + n) * 8];
#define STEP2(af, bf)                                                          \
  _Pragma("unroll") for (int mt = 0; mt < 4; mt++)                             \
      _Pragma("unroll") for (int nt = 0; nt < 4; nt++)                         \
          acc[mt][nt] = __builtin_amdgcn_mfma_f32_16x16x32_f16(                \
              af[mt], bf[nt], acc[mt][nt], 0, 0, 0);

  f16x8 aA[4], aB[4], bC[4], bD[4];
  LDA2(aA, 0)
#pragma unroll
  for (int ks = 0; ks < 12; ks += 2) {
    if (ks + 1 < 12) LDA2(aB, ks + 1)
    LDBS2(bC, ks)
    STEP2(aA, bC)
    if (ks + 2 < 12) LDA2(aA, ks + 2)
    if (ks + 1 < 12) { LDBS2(bD, ks + 1) STEP2(aB, bD) }
  }
#undef LDA2
#undef LDBS2
#undef STEP2

#pragma unroll
  for (int mt = 0; mt < 4; mt++) {
    int obase = w * 64 + mt * 16 + q * 4;
#pragma unroll
    for (int nt = 0; nt < 4; nt++) {
      int p = p0 + nt * 16 + n;
#pragma unroll
      for (int r = 0; r < 4; r++) {
        size_t idx = ((size_t)b * O + obase + r) * HW + p;
        out[idx] = acc[mt][nt][r];
      }
    }
  }
}

// ---------------------------------------------------------------------------
extern "C" void kernel_launch(void* const* d_in, const int* in_sizes, int n_in,
                              void* d_out, int out_size, void* d_ws, size_t ws_size,
                              hipStream_t stream) {
  const float* x     = (const float*)d_in[0];
  const float* pw1_w = (const float*)d_in[1];
  const float* pw1_b = (const float*)d_in[2];
  const float* fc1_w = (const float*)d_in[3];
  const float* fc1_b = (const float*)d_in[4];
  const float* fc2_w = (const float*)d_in[5];
  const float* fc2_b = (const float*)d_in[6];
  const float* off_w = (const float*)d_in[7];
  const float* off_b = (const float*)d_in[8];
  const float* dw3   = (const float*)d_in[9];
  const float* dw5   = (const float*)d_in[10];
  const float* dw7   = (const float*)d_in[11];
  const float* pw_w  = (const float*)d_in[12];
  const float* pw_b  = (const float*)d_in[13];
  float* out = (float*)d_out;
  float* ws  = (float*)d_ws;

  kT<<<384, 256, 0, stream>>>(pw1_w, pw_w, fc1_w, fc2_w, ws);
  kAT<<<dim3(HW / 256, 32, B), 256, 0, stream>>>(x, ws);
  kB<<<B, 256, 0, stream>>>(pw1_w, pw1_b, fc1_w, fc1_b, fc2_w, fc2_b, ws);
  kCm<<<dim3(HW / 64, 1, B), 256, 0, stream>>>(pw1_b, ws);
  kD1<<<1, 256, 0, stream>>>(off_w, off_b, ws);
  kD2<<<84, 256, 0, stream>>>(dw3, dw5, dw7, ws);
  kEm<<<dim3(32, 16, B), 256, 0, stream>>>(ws, ws);
  kFm<<<dim3(HW / 64, 1, B), 256, 0, stream>>>(x, pw_b, ws, out);
}

// Round 11
// 533.088 us; speedup vs baseline: 1.0469x; 1.0264x over previous
//
#include <hip/hip_runtime.h>
#include <math.h>

// Problem constants
constexpr int B  = 8;
constexpr int C  = 256;   // Cin
constexpr int M  = 256;
constexpr int O  = 256;
constexpr int H  = 128;
constexpr int W  = 128;
constexpr int HW = H * W; // 16384
constexpr int K  = 128;   // top-k / kept channels

using f16   = _Float16;
using f16x2 = __attribute__((ext_vector_type(2))) _Float16;
using f16x8 = __attribute__((ext_vector_type(8))) _Float16;
using f32x4 = __attribute__((ext_vector_type(4))) float;

// Workspace layout (offsets in float units)
constexpr size_t WS_MEANX = 0;        // 2048
constexpr size_t WS_MASK  = 2048;     // 2048
constexpr size_t WS_G2    = 4096;     // 2048
constexpr size_t WS_OFF   = 6144;     // 48 (pad to 64) [unused now]
constexpr size_t WS_WE3   = 6208;     // 9216
constexpr size_t WS_WE5   = 15424;    // 25600
constexpr size_t WS_WE7   = 41024;    // 50176
constexpr size_t WS_WT1G  = 91200;    // 65536 f16 (pw1_w fragment-linear)
constexpr size_t WS_WT2G  = 123968;   // 98304 f16 (pw_w[:, :384] fragment-linear)
constexpr size_t WS_SELH  = 173120;   // B*K*HW f16 = 8388608 float slots (33.5 MB)
// BIG region: union of xh (B*C*HW f16, dead after kCm) and yh2 (3*B*K*HW f16)
constexpr size_t WS_BIG   = 8561728;
// end = 33727552 floats = 134.91 MB (same proven footprint as before)

// ---------------------------------------------------------------------------
// Kernel T: fragment-linear f16 weight copies + zero meanx/gap2sum.
// Also warm-read fc1_w/fc2_w into L3 for kB.
// ---------------------------------------------------------------------------
__global__ __launch_bounds__(256) void kT(const float* __restrict__ pw1_w,
                                          const float* __restrict__ pw_w,
                                          const float* __restrict__ fc1_w,
                                          const float* __restrict__ fc2_w,
                                          float* __restrict__ ws) {
  f16* wt1g = (f16*)(ws + WS_WT1G);
  f16* wt2g = (f16*)(ws + WS_WT2G);
  int t = blockIdx.x * 256 + threadIdx.x;
  if (t < 65536) {
    int ks = t >> 13, fr = (t >> 9) & 15, l = (t >> 3) & 63, j = t & 7;
    int o = fr * 16 + (l & 15);
    int c = ks * 32 + ((l >> 4) << 3) + j;
    wt1g[t] = (f16)pw1_w[o * C + c];
  }
  if (t < 98304) {
    int ks = t >> 13, fr = (t >> 9) & 15, l = (t >> 3) & 63, j = t & 7;
    int o = fr * 16 + (l & 15);
    int cc = ks * 32 + ((l >> 4) << 3) + j;
    wt2g[t] = (f16)pw_w[(size_t)o * 768 + cc];
  }
  if (t < 2048) {
    ws[WS_MEANX + t] = 0.f;
    ws[WS_G2 + t]    = 0.f;
  }
  // L3 warm for kB: fc1_w (512x256) + fc2_w (256x512), 32768 float4 each.
  if (t < 32768) {
    float4 a = ((const float4*)fc1_w)[t];
    float4 c = ((const float4*)fc2_w)[t];
    float dead = a.x + a.y + a.z + a.w + c.x + c.y + c.z + c.w;
    asm volatile("" :: "v"(dead));  // keep reads live without storing
  }
}

// ---------------------------------------------------------------------------
// Kernel AT: read x once; per-channel means (atomic partials) and xh = f16 x
// in octet-interleaved layout xh[((b*32+ko)*HW + p)*8 + j], k = 8ko+j.
// ---------------------------------------------------------------------------
__global__ __launch_bounds__(256) void kAT(const float* __restrict__ x,
                                           float* __restrict__ ws) {
  float* meanx = ws + WS_MEANX;
  f16* xh      = (f16*)(ws + WS_BIG);
  int b = blockIdx.z, ko = blockIdx.y, p0 = blockIdx.x * 256;
  __shared__ float sx[8][256];
  int t = threadIdx.x;
  int c8 = t >> 5, pg = t & 31;
  const float* xp = x + (size_t)(b * 256 + ko * 8 + c8) * HW + p0 + pg * 8;
  float4 v0 = ((const float4*)xp)[0];
  float4 v1 = ((const float4*)xp)[1];
  *(float4*)&sx[c8][pg * 8]     = v0;
  *(float4*)&sx[c8][pg * 8 + 4] = v1;
  float s = v0.x + v0.y + v0.z + v0.w + v1.x + v1.y + v1.z + v1.w;
#pragma unroll
  for (int off = 16; off > 0; off >>= 1) s += __shfl_xor(s, off, 32);
  if (pg == 0) atomicAdd(&meanx[b * 256 + ko * 8 + c8], s * (1.f / HW));
  __syncthreads();
  f16x8 o;
#pragma unroll
  for (int j = 0; j < 8; j++) o[j] = (f16)sx[j][t];
  *(f16x8*)&xh[((size_t)(b * 32 + ko) * HW + p0 + t) * 8] = o;
}

// ---------------------------------------------------------------------------
// Kernel B: per-batch block; exact fp32 scoring path (unchanged).
// ---------------------------------------------------------------------------
__global__ __launch_bounds__(256) void kB(const float* __restrict__ pw1_w,
                                          const float* __restrict__ pw1_b,
                                          const float* __restrict__ fc1_w,
                                          const float* __restrict__ fc1_b,
                                          const float* __restrict__ fc2_w,
                                          const float* __restrict__ fc2_b,
                                          float* __restrict__ ws) {
  int b = blockIdx.x;
  const float* meanx = ws + WS_MEANX + b * C;
  float* maskg = ws + WS_MASK;
  __shared__ float s_gap[M];
  __shared__ float s_hid[512];
  __shared__ float s_sc[M];
  int t = threadIdx.x;
  int lane = t & 63, wv = t >> 6;

  float4 mx = ((const float4*)meanx)[lane];
  for (int o0 = wv * 64; o0 < wv * 64 + 64; o0 += 4) {
    float s[4];
#pragma unroll
    for (int j = 0; j < 4; j++) {
      float4 w = ((const float4*)(pw1_w + (size_t)(o0 + j) * C))[lane];
      s[j] = mx.x * w.x + mx.y * w.y + mx.z * w.z + mx.w * w.w;
    }
#pragma unroll
    for (int off = 32; off > 0; off >>= 1)
#pragma unroll
      for (int j = 0; j < 4; j++) s[j] += __shfl_xor(s[j], off, 64);
    if (lane == 0) {
#pragma unroll
      for (int j = 0; j < 4; j++) s_gap[o0 + j] = s[j] + pw1_b[o0 + j];
    }
  }
  __syncthreads();

  float4 g4 = ((const float4*)s_gap)[lane];
  for (int j0 = wv * 128; j0 < wv * 128 + 128; j0 += 4) {
    float s[4];
#pragma unroll
    for (int j = 0; j < 4; j++) {
      float4 w = ((const float4*)(fc1_w + (size_t)(j0 + j) * M))[lane];
      s[j] = g4.x * w.x + g4.y * w.y + g4.z * w.z + g4.w * w.w;
    }
#pragma unroll
    for (int off = 32; off > 0; off >>= 1)
#pragma unroll
      for (int j = 0; j < 4; j++) s[j] += __shfl_xor(s[j], off, 64);
    if (lane == 0) {
#pragma unroll
      for (int j = 0; j < 4; j++) {
        float v = s[j] + fc1_b[j0 + j];
        s_hid[j0 + j] = v > 0.f ? v : 0.f;
      }
    }
  }
  __syncthreads();

  float4 h0 = ((const float4*)s_hid)[lane];
  float4 h1 = ((const float4*)s_hid)[lane + 64];
  for (int o0 = wv * 64; o0 < wv * 64 + 64; o0 += 4) {
    float s[4];
#pragma unroll
    for (int j = 0; j < 4; j++) {
      const float4* wr = (const float4*)(fc2_w + (size_t)(o0 + j) * 512);
      float4 w0 = wr[lane];
      float4 w1 = wr[lane + 64];
      s[j] = h0.x * w0.x + h0.y * w0.y + h0.z * w0.z + h0.w * w0.w +
             h1.x * w1.x + h1.y * w1.y + h1.z * w1.z + h1.w * w1.w;
    }
#pragma unroll
    for (int off = 32; off > 0; off >>= 1)
#pragma unroll
      for (int j = 0; j < 4; j++) s[j] += __shfl_xor(s[j], off, 64);
    if (lane == 0) {
#pragma unroll
      for (int j = 0; j < 4; j++) {
        float v = s[j] + fc2_b[o0 + j];
        s_sc[o0 + j] = 1.f / (1.f + expf(-v));
      }
    }
  }
  __syncthreads();

  {
    int j = t;
    float sj = s_sc[j];
    int cnt = 0;
    for (int m = 0; m < M; m++) {
      float sm = s_sc[m];
      cnt += (sm > sj) || (sm == sj && m < j);
    }
    maskg[b * M + j] = (cnt < K) ? 1.f : 0.f;
  }
}

// ---------------------------------------------------------------------------
// Kernel Cm: h = relu(pw1(x)) via f16 MFMA. 512-thread blocks: o-dim split
// across 8 waves (32 o x 64 px each, acc[2][4]). Same 32 KB B-tile staged
// once per block -> stage/barrier cost amortized over 8 waves, and LDS
// 32 KB x 4 blocks/CU = up to 32 waves/CU (was 8). TLP attack on the
// latency-bound plateau (occupancy 24% across R5-R10).
// ---------------------------------------------------------------------------
__global__ __launch_bounds__(512) void kCm(const float* __restrict__ pw1_b,
                                           float* __restrict__ ws) {
  const f16* wt1g = (const f16*)(ws + WS_WT1G);
  const f16* xh   = (const f16*)(ws + WS_BIG);
  float* gap2sum  = ws + WS_G2;
  f16* selh       = (f16*)(ws + WS_SELH);
  __shared__ f16 Bs[32 * 512];  // [chunk ko 0..31][px 0..63][8 f16] = 32 KB
  int b  = blockIdx.z;
  int p0 = blockIdx.x * 64;

  int t = threadIdx.x, l = t & 63, w2 = t >> 6;  // 8 waves
  int q = l >> 4, n = l & 15;

  // Stage B-tile: 4 chunks of 16B per thread.
  {
    f16x8 tmp[4];
#pragma unroll
    for (int i = 0; i < 4; i++) {
      int s = t + i * 512;
      int ko = s >> 6, ll = s & 63;
      tmp[i] = *(const f16x8*)&xh[((size_t)(b * 32 + ko) * HW + p0 + ll) * 8];
    }
#pragma unroll
    for (int i = 0; i < 4; i++)
      *(f16x8*)&Bs[(size_t)(t + i * 512) * 8] = tmp[i];
  }

  f32x4 acc[2][4];
#pragma unroll
  for (int mt = 0; mt < 2; mt++) {
    int obase = w2 * 32 + mt * 16 + q * 4;
#pragma unroll
    for (int nt = 0; nt < 4; nt++)
#pragma unroll
      for (int r = 0; r < 4; r++) acc[mt][nt][r] = pw1_b[obase + r];
  }
  __syncthreads();

  const f16* abase = wt1g + (size_t)(w2 * 2) * 512 + (size_t)l * 8;

#define LDA1(dst, ks)                                                          \
  _Pragma("unroll") for (int mt = 0; mt < 2; mt++)                             \
      dst[mt] = *(const f16x8*)(abase + (size_t)((ks) * 16 + mt) * 512);
#define LDBS1(dst, ks)                                                         \
  _Pragma("unroll") for (int nt = 0; nt < 4; nt++)                             \
      dst[nt] = *(const f16x8*)&Bs[(size_t)(((ks) * 4 + q) * 64 + nt * 16 + n) * 8];
#define STEP1(af, bf)                                                          \
  _Pragma("unroll") for (int mt = 0; mt < 2; mt++)                             \
      _Pragma("unroll") for (int nt = 0; nt < 4; nt++)                         \
          acc[mt][nt] = __builtin_amdgcn_mfma_f32_16x16x32_f16(                \
              af[mt], bf[nt], acc[mt][nt], 0, 0, 0);

  f16x8 aA[2], aB[2], bC[4], bD[4];
  LDA1(aA, 0)
#pragma unroll
  for (int ks = 0; ks < 8; ks += 2) {
    if (ks + 1 < 8) LDA1(aB, ks + 1)
    LDBS1(bC, ks)
    STEP1(aA, bC)
    if (ks + 2 < 8) LDA1(aA, ks + 2)
    if (ks + 1 < 8) { LDBS1(bD, ks + 1) STEP1(aB, bD) }
  }
#undef LDA1
#undef LDBS1
#undef STEP1

  // Epilogue: relu; sel f16 store (o<128); gap2sum partial sums
#pragma unroll
  for (int mt = 0; mt < 2; mt++) {
    float rsum[4] = {0.f, 0.f, 0.f, 0.f};
    int obase = w2 * 32 + mt * 16 + q * 4;
#pragma unroll
    for (int nt = 0; nt < 4; nt++) {
      int p = p0 + nt * 16 + n;
#pragma unroll
      for (int r = 0; r < 4; r++) {
        float h = acc[mt][nt][r];
        h = h > 0.f ? h : 0.f;
        rsum[r] += h;
        int o = obase + r;
        if (o < K) selh[((size_t)(b * K + o)) * HW + p] = (f16)h;
      }
    }
#pragma unroll
    for (int off = 1; off < 16; off <<= 1)
#pragma unroll
      for (int r = 0; r < 4; r++) rsum[r] += __shfl_xor(rsum[r], off, 64);
    if (n == 0) {
#pragma unroll
      for (int r = 0; r < 4; r++)
        atomicAdd(&gap2sum[b * M + obase + r], rsum[r]);
    }
  }
}

// ---------------------------------------------------------------------------
// Kernel D2: offsets (computed redundantly per block from gap2sum — replaces
// kD1, removes one launch) + effective depthwise weights with top-k mask.
// ---------------------------------------------------------------------------
__global__ __launch_bounds__(256) void kD2(const float* __restrict__ dw3,
                                           const float* __restrict__ dw5,
                                           const float* __restrict__ dw7,
                                           const float* __restrict__ off_w,
                                           const float* __restrict__ off_b,
                                           float* __restrict__ ws) {
  const float* gap2sum = ws + WS_G2;
  const float* maskg   = ws + WS_MASK;
  float* wE3 = ws + WS_WE3;
  float* wE5 = ws + WS_WE5;
  float* wE7 = ws + WS_WE7;
  __shared__ float s_off[48];   // tanh(gap2 @ off_w + b)
  __shared__ float offv[48];    // [0..23]=scale(b*3+i), [24..47]=shift
  int t = threadIdx.x;
  int lane = t & 63, wv = t >> 6;
  for (int id = wv; id < 48; id += 4) {
    int b = id / 6, j = id % 6;
    float4 g = ((const float4*)(gap2sum + b * M))[lane];
    float4 w = ((const float4*)(off_w + (size_t)j * M))[lane];
    float s = (g.x * w.x + g.y * w.y + g.z * w.z + g.w * w.w) * (1.f / HW);
#pragma unroll
    for (int off = 32; off > 0; off >>= 1) s += __shfl_xor(s, off, 64);
    if (lane == 0) s_off[id] = tanhf(s + off_b[j]);
  }
  __syncthreads();
  if (t < 24) {
    int b = t / 3, i = t % 3;
    offv[t]      = 1.f + 1.f / (1.f + expf(-s_off[b * 6 + 2 * i]));
    offv[24 + t] = tanhf(s_off[b * 6 + 2 * i + 1]);
  }
  __syncthreads();

  int tid = blockIdx.x * 256 + t;
  int stride = gridDim.x * 256;
  for (int i = tid; i < B * K * 9; i += stride) {
    int b = i / (K * 9), rem = i % (K * 9), c = rem / 9;
    wE3[i] = (dw3[rem] * offv[b * 3 + 0] + offv[24 + b * 3 + 0]) * maskg[b * M + c];
  }
  for (int i = tid; i < B * K * 25; i += stride) {
    int b = i / (K * 25), rem = i % (K * 25), c = rem / 25;
    wE5[i] = (dw5[rem] * offv[b * 3 + 1] + offv[24 + b * 3 + 1]) * maskg[b * M + c];
  }
  for (int i = tid; i < B * K * 49; i += stride) {
    int b = i / (K * 49), rem = i % (K * 49), c = rem / 49;
    wE7[i] = (dw7[rem] * offv[b * 3 + 2] + offv[24 + b * 3 + 2]) * maskg[b * M + c];
  }
}

// ---------------------------------------------------------------------------
// Kernel Em: merged depthwise conv. 8-row slabs, 18 KB LDS, conflict-free
// stride; f16x8 vectorized halo fill. (R10-proven form, unchanged.)
// ---------------------------------------------------------------------------
__global__ __launch_bounds__(256) void kEm(const float* __restrict__ ws_ro,
                                           float* __restrict__ ws) {
  constexpr int SP = 1128;  // f16 per channel plane (14 rows x 80 + pad)
  __shared__ f16 sm[8 * SP];  // 18048 B
  const f16* selh = (const f16*)(ws_ro + WS_SELH);
  f16* yh2        = (f16*)(ws + WS_BIG);
  int bx = blockIdx.x;
  int slab = bx >> 1, chalf = bx & 1;
  int ko = blockIdx.y, b = blockIdx.z;
  int r0 = slab * 8, c0 = chalf * 64;

  for (int i = threadIdx.x; i < 8 * 140; i += 256) {
    int chn = i / 140, rem = i - chn * 140;
    int rr = rem / 10, chunk = rem - rr * 10;
    int gy = r0 - 3 + rr, g0 = c0 - 8 + chunk * 8;
    f16x8 v = {};
    if (gy >= 0 && gy < H && g0 >= 0 && g0 < W)
      v = *(const f16x8*)&selh[(size_t)(b * 128 + ko * 8 + chn) * HW + gy * W + g0];
    *(f16x8*)&sm[chn * SP + rr * 80 + chunk * 8] = v;
  }
  __syncthreads();

  int t = threadIdx.x;
  int ch = t & 7, cp = t >> 3;  // channel 0..7, col-pair 0..31
  int cglob = c0 + cp * 2;

#define CONV_BRANCH(KS, BR, WSOFF, NW, SOFF)                                   \
  {                                                                            \
    constexpr int P = (KS - 1) / 2;                                            \
    const float* wp = ws_ro + WSOFF + (size_t)(b * 128 + ko * 8 + ch) * (KS*KS); \
    float w[KS * KS];                                                          \
    _Pragma("unroll") for (int i = 0; i < KS * KS; i++) w[i] = wp[i];          \
    float a0[8], a1[8];                                                        \
    _Pragma("unroll") for (int r = 0; r < 8; r++) { a0[r] = 0.f; a1[r] = 0.f; } \
    _Pragma("unroll") for (int iy = 0; iy < 8 + 2 * P; iy++) {                 \
      int hr = iy + (3 - P);                                                   \
      const f16x2* rowp = (const f16x2*)(sm + ch * SP + hr * 80);              \
      float vv[2 * NW];                                                        \
      _Pragma("unroll") for (int u = 0; u < NW; u++) {                         \
        f16x2 pr = rowp[cp + SOFF + u];                                        \
        vv[2 * u]     = (float)pr[0];                                          \
        vv[2 * u + 1] = (float)pr[1];                                          \
      }                                                                        \
      _Pragma("unroll") for (int rr = 0; rr < 8; rr++) {                       \
        int dy = iy - rr;                                                      \
        if (dy >= 0 && dy < KS) {                                              \
          _Pragma("unroll") for (int dx = 0; dx < KS; dx++) {                  \
            int m = (8 - P) + dx - 2 * SOFF;                                   \
            a0[rr] += vv[m]     * w[dy * KS + dx];                             \
            a1[rr] += vv[m + 1] * w[dy * KS + dx];                             \
          }                                                                    \
        }                                                                      \
      }                                                                        \
    }                                                                          \
    f16* op = yh2 + (size_t)(b * 48 + BR * 16 + ko) * HW * 8;                  \
    _Pragma("unroll") for (int rr = 0; rr < 8; rr++) {                         \
      size_t pa = ((size_t)(r0 + rr) * W + cglob) * 8 + ch;                    \
      op[pa]     = (f16)a0[rr];                                                \
      op[pa + 8] = (f16)a1[rr];                                                \
    }                                                                          \
  }

  CONV_BRANCH(3, 0, WS_WE3, 3, 3)
  CONV_BRANCH(5, 1, WS_WE5, 3, 3)
  CONV_BRANCH(7, 2, WS_WE7, 5, 2)
#undef CONV_BRANCH
}

// ---------------------------------------------------------------------------
// Kernel Fm: merged final pointwise, f16 MFMA, K=384. 512-thread blocks,
// o split across 8 waves (acc[2][4]); 48 KB B-tile staged once per block ->
// 3 blocks x 8 waves = 24 waves/CU (was 12). Residual + bias folded into
// acc init (nontemporal x loads complete under the staging barrier).
// ---------------------------------------------------------------------------
__global__ __launch_bounds__(512) void kFm(const float* __restrict__ x,
                                           const float* __restrict__ pw_b,
                                           const float* __restrict__ ws,
                                           float* __restrict__ out) {
  const f16* wt2g = (const f16*)(ws + WS_WT2G);
  const f16* yh2  = (const f16*)(ws + WS_BIG);
  __shared__ f16 Bs[48 * 512];  // [chunk 0..47][px 0..63][8 f16] = 48 KB
  int b  = blockIdx.z;
  int p0 = blockIdx.x * 64;

  int t = threadIdx.x, l = t & 63, w2 = t >> 6;  // 8 waves
  int q = l >> 4, n = l & 15;

  // Stage B-tile: 6 chunks of 16B per thread.
  {
    f16x8 tmp[6];
#pragma unroll
    for (int i = 0; i < 6; i++) {
      int s = t + i * 512;
      int ko = s >> 6, ll = s & 63;
      tmp[i] = *(const f16x8*)&yh2[((size_t)(b * 48 + ko) * HW + p0 + ll) * 8];
    }
#pragma unroll
    for (int i = 0; i < 6; i++)
      *(f16x8*)&Bs[(size_t)(t + i * 512) * 8] = tmp[i];
  }

  f32x4 acc[2][4];
#pragma unroll
  for (int mt = 0; mt < 2; mt++) {
    int obase = w2 * 32 + mt * 16 + q * 4;
    float b4[4];
#pragma unroll
    for (int r = 0; r < 4; r++) b4[r] = pw_b[obase + r];
#pragma unroll
    for (int nt = 0; nt < 4; nt++) {
      int p = p0 + nt * 16 + n;
#pragma unroll
      for (int r = 0; r < 4; r++) {
        size_t idx = ((size_t)b * O + obase + r) * HW + p;
        acc[mt][nt][r] = b4[r] + __builtin_nontemporal_load(&x[idx]);
      }
    }
  }
  __syncthreads();

  const f16* abase = wt2g + (size_t)(w2 * 2) * 512 + (size_t)l * 8;

#define LDA2(dst, ks)                                                          \
  _Pragma("unroll") for (int mt = 0; mt < 2; mt++)                             \
      dst[mt] = *(const f16x8*)(abase + (size_t)((ks) * 16 + mt) * 512);
#define LDBS2(dst, ks)                                                         \
  _Pragma("unroll") for (int nt = 0; nt < 4; nt++)                             \
      dst[nt] = *(const f16x8*)&Bs[(size_t)(((ks) * 4 + q) * 64 + nt * 16 + n) * 8];
#define STEP2(af, bf)                                                          \
  _Pragma("unroll") for (int mt = 0; mt < 2; mt++)                             \
      _Pragma("unroll") for (int nt = 0; nt < 4; nt++)                         \
          acc[mt][nt] = __builtin_amdgcn_mfma_f32_16x16x32_f16(                \
              af[mt], bf[nt], acc[mt][nt], 0, 0, 0);

  f16x8 aA[2], aB[2], bC[4], bD[4];
  LDA2(aA, 0)
#pragma unroll
  for (int ks = 0; ks < 12; ks += 2) {
    if (ks + 1 < 12) LDA2(aB, ks + 1)
    LDBS2(bC, ks)
    STEP2(aA, bC)
    if (ks + 2 < 12) LDA2(aA, ks + 2)
    if (ks + 1 < 12) { LDBS2(bD, ks + 1) STEP2(aB, bD) }
  }
#undef LDA2
#undef LDBS2
#undef STEP2

#pragma unroll
  for (int mt = 0; mt < 2; mt++) {
    int obase = w2 * 32 + mt * 16 + q * 4;
#pragma unroll
    for (int nt = 0; nt < 4; nt++) {
      int p = p0 + nt * 16 + n;
#pragma unroll
      for (int r = 0; r < 4; r++) {
        size_t idx = ((size_t)b * O + obase + r) * HW + p;
        out[idx] = acc[mt][nt][r];
      }
    }
  }
}

// ---------------------------------------------------------------------------
extern "C" void kernel_launch(void* const* d_in, const int* in_sizes, int n_in,
                              void* d_out, int out_size, void* d_ws, size_t ws_size,
                              hipStream_t stream) {
  const float* x     = (const float*)d_in[0];
  const float* pw1_w = (const float*)d_in[1];
  const float* pw1_b = (const float*)d_in[2];
  const float* fc1_w = (const float*)d_in[3];
  const float* fc1_b = (const float*)d_in[4];
  const float* fc2_w = (const float*)d_in[5];
  const float* fc2_b = (const float*)d_in[6];
  const float* off_w = (const float*)d_in[7];
  const float* off_b = (const float*)d_in[8];
  const float* dw3   = (const float*)d_in[9];
  const float* dw5   = (const float*)d_in[10];
  const float* dw7   = (const float*)d_in[11];
  const float* pw_w  = (const float*)d_in[12];
  const float* pw_b  = (const float*)d_in[13];
  float* out = (float*)d_out;
  float* ws  = (float*)d_ws;

  kT<<<384, 256, 0, stream>>>(pw1_w, pw_w, fc1_w, fc2_w, ws);
  kAT<<<dim3(HW / 256, 32, B), 256, 0, stream>>>(x, ws);
  kB<<<B, 256, 0, stream>>>(pw1_w, pw1_b, fc1_w, fc1_b, fc2_w, fc2_b, ws);
  kCm<<<dim3(HW / 64, 1, B), 512, 0, stream>>>(pw1_b, ws);
  kD2<<<84, 256, 0, stream>>>(dw3, dw5, dw7, off_w, off_b, ws);
  kEm<<<dim3(32, 16, B), 256, 0, stream>>>(ws, ws);
  kFm<<<dim3(HW / 64, 1, B), 512, 0, stream>>>(x, pw_b, ws, out);
}